// Round 1
// baseline (1023.196 us; speedup 1.0000x reference)
//
#include <hip/hip_runtime.h>

#define D_MODEL 4096
#define NEXP    64
#define NTOK    16384            // 4 * 4096
#define BK      128              // K-chunk staged in LDS
#define BKP     (BK + 4)         // padded row stride (floats): uniform bank spread for b128 reads
#define TPW     8                // tokens per wave
#define WPB     4                // waves per block
#define TPB     (TPW * WPB)      // 32 tokens per block

// ---- W pre-transpose: W[d][e] (4096x64) -> Wt[e][d] (64x4096) in workspace ----
__global__ __launch_bounds__(256) void transpose_w(const float* __restrict__ W,
                                                   float* __restrict__ Wt) {
    __shared__ float tile[64][65];
    const int d0  = blockIdx.x * 64;
    const int tid = threadIdx.x;
#pragma unroll
    for (int j = 0; j < 16; j++) {
        int lin = j * 256 + tid;              // 0..4095
        int r = lin >> 6, e = lin & 63;
        tile[r][e] = W[(size_t)(d0 + r) * NEXP + e];   // coalesced read
    }
    __syncthreads();
#pragma unroll
    for (int j = 0; j < 16; j++) {
        int lin = j * 256 + tid;
        int e = lin >> 6, c = lin & 63;
        Wt[(size_t)e * D_MODEL + d0 + c] = tile[c][e]; // coalesced write, pad breaks conflicts
    }
}

// ---- main: GEMM(lane<->expert, x via scalar loads) + softmax + top2, fused ----
template <bool PRETRANSPOSED>
__global__ __launch_bounds__(256, 2) void router_main(
    const float* __restrict__ x, const float* __restrict__ W,
    const float* __restrict__ Wt, const float* __restrict__ b,
    float* __restrict__ out)
{
    __shared__ float wt[NEXP * BKP];          // 33792 B
    const int tid  = threadIdx.x;
    const int lane = tid & 63;
    const int wv   = __builtin_amdgcn_readfirstlane(tid >> 6);  // provably uniform
    const int tok0 = blockIdx.x * TPB + wv * TPW;
    const float* __restrict__ xw = x + (size_t)tok0 * D_MODEL;  // uniform ptr -> s_load path

    float accm[TPW];
#pragma unroll
    for (int t = 0; t < TPW; t++) accm[t] = 0.f;

    for (int k0 = 0; k0 < D_MODEL; k0 += BK) {
        // stage W chunk into LDS, layout wt[e][kk] (row stride BKP)
        if (PRETRANSPOSED) {
#pragma unroll
            for (int i = 0; i < 8; i++) {
                int n = i * 256 + tid;        // float4 slot 0..2047
                int e = n >> 5;               // 32 float4 per expert row
                int s = n & 31;
                float4 v = *(const float4*)(Wt + (size_t)e * D_MODEL + k0 + 4 * s);
                *(float4*)(&wt[e * BKP + 4 * s]) = v;   // conflict-free b128 write
            }
        } else {
            // fallback (no workspace): natural-layout read, scattered b32 writes (slower)
#pragma unroll
            for (int i = 0; i < 8; i++) {
                int n  = (i * 256 + tid) * 4; // linear element in chunk
                int dd = n >> 6;
                int e0 = n & 63;
                float4 v = *(const float4*)(W + (size_t)(k0 + dd) * NEXP + e0);
                wt[(e0 + 0) * BKP + dd] = v.x;
                wt[(e0 + 1) * BKP + dd] = v.y;
                wt[(e0 + 2) * BKP + dd] = v.z;
                wt[(e0 + 3) * BKP + dd] = v.w;
            }
        }
        __syncthreads();

        float acc[TPW];
#pragma unroll
        for (int t = 0; t < TPW; t++) acc[t] = 0.f;

        const float* wl = &wt[lane * BKP];
#pragma unroll 2
        for (int kk = 0; kk < BK; kk += 4) {
            float4 w4 = *(const float4*)(wl + kk);      // ds_read_b128, reused by 8 tokens
#pragma unroll
            for (int t = 0; t < TPW; t++) {
                const float* xr = xw + (size_t)t * D_MODEL + k0 + kk;  // uniform -> SGPR
                float a = acc[t];
                a = fmaf(xr[0], w4.x, a);
                a = fmaf(xr[1], w4.y, a);
                a = fmaf(xr[2], w4.z, a);
                a = fmaf(xr[3], w4.w, a);
                acc[t] = a;
            }
        }
#pragma unroll
        for (int t = 0; t < TPW; t++) accm[t] += acc[t];  // two-level sum: less rounding drift
        __syncthreads();
    }

    // ---- epilogue: bias + softmax + top2 (+renorm), lane <-> expert ----
    const float bias = b[lane];
    float* __restrict__ probs_out = out;
    float* __restrict__ top_out   = out + (size_t)NTOK * NEXP;
    float* __restrict__ idx_out   = out + (size_t)NTOK * NEXP + (size_t)NTOK * 2;

#pragma unroll 1
    for (int t = 0; t < TPW; t++) {
        const int token = tok0 + t;
        float logit = accm[t] + bias;

        float m = logit;
#pragma unroll
        for (int off = 32; off; off >>= 1) m = fmaxf(m, __shfl_xor(m, off, 64));
        float ex = expf(logit - m);
        float s = ex;
#pragma unroll
        for (int off = 32; off; off >>= 1) s += __shfl_xor(s, off, 64);
        float p = ex / s;
        probs_out[(size_t)token * NEXP + lane] = p;       // coalesced

        // top-1 (lowest index wins ties, matching lax.top_k)
        float v = p; int idx = lane;
#pragma unroll
        for (int off = 32; off; off >>= 1) {
            float ov = __shfl_xor(v, off, 64);
            int   oi = __shfl_xor(idx, off, 64);
            if (ov > v || (ov == v && oi < idx)) { v = ov; idx = oi; }
        }
        const float v1 = v; const int i1 = idx;
        // top-2
        v = (lane == i1) ? -1.0f : p; idx = lane;
#pragma unroll
        for (int off = 32; off; off >>= 1) {
            float ov = __shfl_xor(v, off, 64);
            int   oi = __shfl_xor(idx, off, 64);
            if (ov > v || (ov == v && oi < idx)) { v = ov; idx = oi; }
        }
        const float v2 = v; const int i2 = idx;

        if (lane == 0) {
            const float dnm = v1 + v2 + 1e-9f;
            top_out[(size_t)token * 2 + 0] = v1 / dnm;
            top_out[(size_t)token * 2 + 1] = v2 / dnm;
            idx_out[(size_t)token * 2 + 0] = (float)i1;   // out buffer is fp32-typed
            idx_out[(size_t)token * 2 + 1] = (float)i2;
        }
    }
}

extern "C" void kernel_launch(void* const* d_in, const int* in_sizes, int n_in,
                              void* d_out, int out_size, void* d_ws, size_t ws_size,
                              hipStream_t stream) {
    const float* x = (const float*)d_in[0];
    const float* W = (const float*)d_in[1];
    const float* b = (const float*)d_in[2];
    float* out = (float*)d_out;

    const size_t wt_bytes = (size_t)NEXP * D_MODEL * sizeof(float);  // 1 MiB
    if (ws_size >= wt_bytes) {
        float* Wt = (float*)d_ws;
        transpose_w<<<D_MODEL / 64, 256, 0, stream>>>(W, Wt);
        router_main<true><<<NTOK / TPB, 256, 0, stream>>>(x, W, Wt, b, out);
    } else {
        router_main<false><<<NTOK / TPB, 256, 0, stream>>>(x, W, nullptr, b, out);
    }
}

// Round 2
// 647.865 us; speedup vs baseline: 1.5793x; 1.5793x over previous
//
#include <hip/hip_runtime.h>

#define D_MODEL 4096
#define NEXP    64
#define NTOK    16384            // 4 * 4096
#define BK      128              // K-chunk staged in LDS
#define BKP     (BK + 4)         // padded row stride (floats): 132 ≡ 4 (mod 32) measured 0-conflict
#define TPW     8                // tokens per wave
#define WPB     2                // waves per block (128-thread blocks -> 1024 blocks)
#define TPB     (TPW * WPB)      // 16 tokens per block
#define NCHUNK  (D_MODEL / BK)   // 32

__device__ __forceinline__ float rl(float v, int l) {
    // wave-uniform lane broadcast: v_readlane_b32 -> SGPR operand of v_fma
    return __int_as_float(__builtin_amdgcn_readlane(__float_as_int(v), l));
}

// ---- W pre-transpose: W[d][e] (4096x64) -> Wt[e][d] (64x4096) in workspace ----
__global__ __launch_bounds__(256) void transpose_w(const float* __restrict__ W,
                                                   float* __restrict__ Wt) {
    __shared__ float tile[64][65];
    const int d0  = blockIdx.x * 64;
    const int tid = threadIdx.x;
#pragma unroll
    for (int j = 0; j < 16; j++) {
        int lin = j * 256 + tid;              // 0..4095
        int r = lin >> 6, e = lin & 63;
        tile[r][e] = W[(size_t)(d0 + r) * NEXP + e];   // coalesced read
    }
    __syncthreads();
#pragma unroll
    for (int j = 0; j < 16; j++) {
        int lin = j * 256 + tid;
        int e = lin >> 6, c = lin & 63;
        Wt[(size_t)e * D_MODEL + d0 + c] = tile[c][e]; // coalesced write
    }
}

// ---- main: lane<->expert GEMM; x via coalesced VMEM + v_readlane broadcast ----
template <bool PRETRANSPOSED>
__global__ __launch_bounds__(128) void router_main(
    const float* __restrict__ x, const float* __restrict__ W,
    const float* __restrict__ Wt, const float* __restrict__ b,
    float* __restrict__ out)
{
    __shared__ float wt[NEXP * BKP];          // 33792 B
    const int tid  = threadIdx.x;
    const int lane = tid & 63;
    const int wv   = __builtin_amdgcn_readfirstlane(tid >> 6);
    const int tok0 = blockIdx.x * TPB + wv * TPW;
    const float* __restrict__ xw = x + (size_t)tok0 * D_MODEL;

    // lane l holds x[t][k0 + 2l], x[t][k0 + 2l + 1] for the current chunk
    float2 xcur[TPW], xnxt[TPW];
#pragma unroll
    for (int t = 0; t < TPW; t++)
        xcur[t] = *(const float2*)(xw + (size_t)t * D_MODEL + 2 * lane);

    float accm[TPW];
#pragma unroll
    for (int t = 0; t < TPW; t++) accm[t] = 0.f;

    for (int c = 0; c < NCHUNK; c++) {
        const int k0 = c * BK;

        // prefetch next x chunk (in flight across this whole chunk's compute)
        if (c + 1 < NCHUNK) {
#pragma unroll
            for (int t = 0; t < TPW; t++)
                xnxt[t] = *(const float2*)(xw + (size_t)t * D_MODEL + (k0 + BK) + 2 * lane);
        }

        // stage W chunk into LDS, layout wt[e][kk] (row stride BKP)
        if (PRETRANSPOSED) {
#pragma unroll
            for (int i = 0; i < 16; i++) {
                int n = i * 128 + tid;        // float4 slot 0..2047
                int e = n >> 5;               // 32 float4 per expert row
                int s = n & 31;
                float4 v = *(const float4*)(Wt + (size_t)e * D_MODEL + k0 + 4 * s);
                *(float4*)(&wt[e * BKP + 4 * s]) = v;   // conflict-free b128 write
            }
        } else {
            // fallback (no workspace): natural-layout read, scattered b32 writes
#pragma unroll
            for (int i = 0; i < 16; i++) {
                int n  = i * 128 + tid;       // float4 slot in [k][e] layout
                int dd = n >> 4;              // 16 float4 per k-row
                int e0 = (n & 15) * 4;
                float4 v = *(const float4*)(W + (size_t)(k0 + dd) * NEXP + e0);
                wt[(e0 + 0) * BKP + dd] = v.x;
                wt[(e0 + 1) * BKP + dd] = v.y;
                wt[(e0 + 2) * BKP + dd] = v.z;
                wt[(e0 + 3) * BKP + dd] = v.w;
            }
        }
        __syncthreads();

        float acc[TPW];
#pragma unroll
        for (int t = 0; t < TPW; t++) acc[t] = 0.f;

        const float* wl = &wt[lane * BKP];
#pragma unroll 4
        for (int kk = 0; kk < BK; kk += 4) {
            float4 w4 = *(const float4*)(wl + kk);      // ds_read_b128, 0 conflicts
            const int l0 = kk >> 1;                     // lane holding k=kk (comp x) and kk+1 (comp y)
#pragma unroll
            for (int t = 0; t < TPW; t++) {
                float a = acc[t];
                a = fmaf(rl(xcur[t].x, l0    ), w4.x, a);
                a = fmaf(rl(xcur[t].y, l0    ), w4.y, a);
                a = fmaf(rl(xcur[t].x, l0 + 1), w4.z, a);
                a = fmaf(rl(xcur[t].y, l0 + 1), w4.w, a);
                acc[t] = a;
            }
        }
#pragma unroll
        for (int t = 0; t < TPW; t++) accm[t] += acc[t];  // two-level sum: less rounding drift
        __syncthreads();
#pragma unroll
        for (int t = 0; t < TPW; t++) xcur[t] = xnxt[t];
    }

    // ---- epilogue: bias + softmax + top2 (+renorm), lane <-> expert ----
    const float bias = b[lane];
    float* __restrict__ probs_out = out;
    float* __restrict__ top_out   = out + (size_t)NTOK * NEXP;
    float* __restrict__ idx_out   = out + (size_t)NTOK * NEXP + (size_t)NTOK * 2;

#pragma unroll 1
    for (int t = 0; t < TPW; t++) {
        const int token = tok0 + t;
        float logit = accm[t] + bias;

        float m = logit;
#pragma unroll
        for (int off = 32; off; off >>= 1) m = fmaxf(m, __shfl_xor(m, off, 64));
        float ex = expf(logit - m);
        float s = ex;
#pragma unroll
        for (int off = 32; off; off >>= 1) s += __shfl_xor(s, off, 64);
        float p = ex / s;
        probs_out[(size_t)token * NEXP + lane] = p;       // coalesced

        // top-1 (lowest index wins ties, matching lax.top_k)
        float v = p; int idx = lane;
#pragma unroll
        for (int off = 32; off; off >>= 1) {
            float ov = __shfl_xor(v, off, 64);
            int   oi = __shfl_xor(idx, off, 64);
            if (ov > v || (ov == v && oi < idx)) { v = ov; idx = oi; }
        }
        const float v1 = v; const int i1 = idx;
        // top-2
        v = (lane == i1) ? -1.0f : p; idx = lane;
#pragma unroll
        for (int off = 32; off; off >>= 1) {
            float ov = __shfl_xor(v, off, 64);
            int   oi = __shfl_xor(idx, off, 64);
            if (ov > v || (ov == v && oi < idx)) { v = ov; idx = oi; }
        }
        const float v2 = v; const int i2 = idx;

        if (lane == 0) {
            const float dnm = v1 + v2 + 1e-9f;
            top_out[(size_t)token * 2 + 0] = v1 / dnm;
            top_out[(size_t)token * 2 + 1] = v2 / dnm;
            idx_out[(size_t)token * 2 + 0] = (float)i1;
            idx_out[(size_t)token * 2 + 1] = (float)i2;
        }
    }
}

extern "C" void kernel_launch(void* const* d_in, const int* in_sizes, int n_in,
                              void* d_out, int out_size, void* d_ws, size_t ws_size,
                              hipStream_t stream) {
    const float* x = (const float*)d_in[0];
    const float* W = (const float*)d_in[1];
    const float* b = (const float*)d_in[2];
    float* out = (float*)d_out;

    const size_t wt_bytes = (size_t)NEXP * D_MODEL * sizeof(float);  // 1 MiB
    if (ws_size >= wt_bytes) {
        float* Wt = (float*)d_ws;
        transpose_w<<<D_MODEL / 64, 256, 0, stream>>>(W, Wt);
        router_main<true><<<NTOK / TPB, WPB * 64, 0, stream>>>(x, W, Wt, b, out);
    } else {
        router_main<false><<<NTOK / TPB, WPB * 64, 0, stream>>>(x, W, nullptr, b, out);
    }
}

// Round 4
// 424.231 us; speedup vs baseline: 2.4119x; 1.5271x over previous
//
#include <hip/hip_runtime.h>

#define D_MODEL 4096
#define NEXP    64
#define NTOK    16384
#define NKS     128              // k-steps of 32: 4096/32

typedef _Float16 half8 __attribute__((ext_vector_type(8)));
typedef float    f32x4 __attribute__((ext_vector_type(4)));

// Dekker-style split of 8 fp32 into f16 hi + f16 lo planes (RTZ; lo catches residual)
__device__ __forceinline__ void split8(float4 a, float4 b, half8& hi, half8& lo) {
    auto h0 = __builtin_amdgcn_cvt_pkrtz(a.x, a.y);
    auto h1 = __builtin_amdgcn_cvt_pkrtz(a.z, a.w);
    auto h2 = __builtin_amdgcn_cvt_pkrtz(b.x, b.y);
    auto h3 = __builtin_amdgcn_cvt_pkrtz(b.z, b.w);
    hi[0] = static_cast<_Float16>(h0[0]); hi[1] = static_cast<_Float16>(h0[1]);
    hi[2] = static_cast<_Float16>(h1[0]); hi[3] = static_cast<_Float16>(h1[1]);
    hi[4] = static_cast<_Float16>(h2[0]); hi[5] = static_cast<_Float16>(h2[1]);
    hi[6] = static_cast<_Float16>(h3[0]); hi[7] = static_cast<_Float16>(h3[1]);
    float r0 = a.x - (float)h0[0], r1 = a.y - (float)h0[1];
    float r2 = a.z - (float)h1[0], r3 = a.w - (float)h1[1];
    float r4 = b.x - (float)h2[0], r5 = b.y - (float)h2[1];
    float r6 = b.z - (float)h3[0], r7 = b.w - (float)h3[1];
    auto l0 = __builtin_amdgcn_cvt_pkrtz(r0, r1);
    auto l1 = __builtin_amdgcn_cvt_pkrtz(r2, r3);
    auto l2 = __builtin_amdgcn_cvt_pkrtz(r4, r5);
    auto l3 = __builtin_amdgcn_cvt_pkrtz(r6, r7);
    lo[0] = static_cast<_Float16>(l0[0]); lo[1] = static_cast<_Float16>(l0[1]);
    lo[2] = static_cast<_Float16>(l1[0]); lo[3] = static_cast<_Float16>(l1[1]);
    lo[4] = static_cast<_Float16>(l2[0]); lo[5] = static_cast<_Float16>(l2[1]);
    lo[6] = static_cast<_Float16>(l3[0]); lo[7] = static_cast<_Float16>(l3[1]);
}

// ---- W prep: split fp32 W[d][e] into f16 hi/lo planes, laid out in exact
// B-fragment order: frag fi = ((ks*4 + tile)*2 + plane), 64 lanes x 16B each.
// Lane l of frag: expert = 16*tile + (l&15), k = ks*32 + (l>>4)*8 + j, j=0..7.
__global__ __launch_bounds__(256) void prep_w(const float* __restrict__ W,
                                              half8* __restrict__ ws) {
    const int gid  = blockIdx.x * 256 + threadIdx.x;   // 0..32767
    const int lane = gid & 63;
    const int fp   = gid >> 6;                         // 0..511 = ks*4 + tile
    const int t    = fp & 3;
    const int ks   = fp >> 2;
    const int e    = 16 * t + (lane & 15);
    const int k0   = ks * 32 + (lane >> 4) * 8;
    float4 a, b;
    a.x = W[(size_t)(k0 + 0) * NEXP + e];
    a.y = W[(size_t)(k0 + 1) * NEXP + e];
    a.z = W[(size_t)(k0 + 2) * NEXP + e];
    a.w = W[(size_t)(k0 + 3) * NEXP + e];
    b.x = W[(size_t)(k0 + 4) * NEXP + e];
    b.y = W[(size_t)(k0 + 5) * NEXP + e];
    b.z = W[(size_t)(k0 + 6) * NEXP + e];
    b.w = W[(size_t)(k0 + 7) * NEXP + e];
    half8 hi, lo;
    split8(a, b, hi, lo);
    ws[(size_t)(fp * 2 + 0) * 64 + lane] = hi;
    ws[(size_t)(fp * 2 + 1) * 64 + lane] = lo;
}

// ---- main: f16-split MFMA GEMM (16 tok x 64 experts per wave) + fused epilogue ----
__global__ __launch_bounds__(256, 1) void router_mfma(
    const float* __restrict__ x, const int4* __restrict__ wf,
    const float* __restrict__ b, float* __restrict__ out)
{
    __shared__ float ls[4][16][68];                    // per-wave logit exchange
    const int tid  = threadIdx.x;
    const int lane = tid & 63;
    const int wv   = tid >> 6;
    const int tok0 = blockIdx.x * 64 + wv * 16;
    const int m    = lane & 15;                        // token row within tile
    const int q    = lane >> 4;                        // quad
    const float* __restrict__ xrow = x + (size_t)(tok0 + m) * D_MODEL + q * 8;

    f32x4 acc[4] = {};                                 // 4 expert tiles x 16x16

    float4 xc[2][2], xn[2][2];                         // [kstep][half]: 8 fp32 each
    int4   wc[2][4][2], wn[2][4][2];                   // [kstep][tile][plane]

    auto ldx = [&](int c, float4 dst[2][2]) {
#pragma unroll
        for (int s = 0; s < 2; s++) {
            const float* p = xrow + (c * 2 + s) * 32;
            dst[s][0] = *(const float4*)p;
            dst[s][1] = *(const float4*)(p + 4);
        }
    };
    auto ldw = [&](int c, int4 dst[2][4][2]) {
#pragma unroll
        for (int s = 0; s < 2; s++) {
            const int ks = c * 2 + s;
#pragma unroll
            for (int t = 0; t < 4; t++) {
                const int fi = (ks * 4 + t) * 2;
                dst[s][t][0] = wf[(size_t)fi * 64 + lane];
                dst[s][t][1] = wf[(size_t)(fi + 1) * 64 + lane];
            }
        }
    };

    ldx(0, xc);
    ldw(0, wc);
#pragma unroll 1
    for (int c = 0; c < 64; c++) {                     // 64 chunks x 2 k-steps
        const int nc = (c < 63) ? c + 1 : 0;           // tail reload is harmless
        ldx(nc, xn);
        ldw(nc, wn);
#pragma unroll
        for (int s = 0; s < 2; s++) {
            half8 ahi, alo;
            split8(xc[s][0], xc[s][1], ahi, alo);
#pragma unroll
            for (int t = 0; t < 4; t++) {
                half8 bhi = __builtin_bit_cast(half8, wc[s][t][0]);
                half8 blo = __builtin_bit_cast(half8, wc[s][t][1]);
                acc[t] = __builtin_amdgcn_mfma_f32_16x16x32_f16(ahi, bhi, acc[t], 0, 0, 0);
                acc[t] = __builtin_amdgcn_mfma_f32_16x16x32_f16(ahi, blo, acc[t], 0, 0, 0);
                acc[t] = __builtin_amdgcn_mfma_f32_16x16x32_f16(alo, bhi, acc[t], 0, 0, 0);
            }
        }
#pragma unroll
        for (int s = 0; s < 2; s++) {
            xc[s][0] = xn[s][0]; xc[s][1] = xn[s][1];
#pragma unroll
            for (int t = 0; t < 4; t++) {
                wc[s][t][0] = wn[s][t][0];
                wc[s][t][1] = wn[s][t][1];
            }
        }
    }

    // C/D layout (verified m89/m91): col = lane&15 (expert), row = q*4 + reg (token)
#pragma unroll
    for (int t = 0; t < 4; t++)
#pragma unroll
        for (int r = 0; r < 4; r++)
            ls[wv][q * 4 + r][t * 16 + m] = acc[t][r];
    // same-wave LDS readback: compiler inserts lgkmcnt wait; no barrier needed

    const float bias = b[lane];
    float* __restrict__ probs_out = out;
    float* __restrict__ top_out   = out + (size_t)NTOK * NEXP;
    float* __restrict__ idx_out   = top_out + (size_t)NTOK * 2;

#pragma unroll 1
    for (int r2 = 0; r2 < 16; r2++) {
        const int token = tok0 + r2;
        float logit = ls[wv][r2][lane] + bias;

        float mx = logit;
#pragma unroll
        for (int off = 32; off; off >>= 1) mx = fmaxf(mx, __shfl_xor(mx, off, 64));
        float ex = expf(logit - mx);
        float s = ex;
#pragma unroll
        for (int off = 32; off; off >>= 1) s += __shfl_xor(s, off, 64);
        float p = ex / s;
        probs_out[(size_t)token * NEXP + lane] = p;

        // top-1 (lowest index wins ties, matching lax.top_k)
        float v = p; int idx = lane;
#pragma unroll
        for (int off = 32; off; off >>= 1) {
            float ov = __shfl_xor(v, off, 64);
            int   oi = __shfl_xor(idx, off, 64);
            if (ov > v || (ov == v && oi < idx)) { v = ov; idx = oi; }
        }
        const float v1 = v; const int i1 = idx;
        // top-2
        v = (lane == i1) ? -1.0f : p; idx = lane;
#pragma unroll
        for (int off = 32; off; off >>= 1) {
            float ov = __shfl_xor(v, off, 64);
            int   oi = __shfl_xor(idx, off, 64);
            if (ov > v || (ov == v && oi < idx)) { v = ov; idx = oi; }
        }
        const float v2 = v; const int i2 = idx;

        if (lane == 0) {
            const float dnm = v1 + v2 + 1e-9f;
            top_out[(size_t)token * 2 + 0] = v1 / dnm;
            top_out[(size_t)token * 2 + 1] = v2 / dnm;
            idx_out[(size_t)token * 2 + 0] = (float)i1;
            idx_out[(size_t)token * 2 + 1] = (float)i2;
        }
    }
}

// ---- fallback (no workspace): round-2 validated structure, W read natural layout ----
#define BK  128
#define BKP (BK + 4)
__device__ __forceinline__ float rl(float v, int l) {
    return __int_as_float(__builtin_amdgcn_readlane(__float_as_int(v), l));
}
__global__ __launch_bounds__(128) void router_fallback(
    const float* __restrict__ x, const float* __restrict__ W,
    const float* __restrict__ b, float* __restrict__ out)
{
    __shared__ float wt[NEXP * BKP];
    const int tid  = threadIdx.x;
    const int lane = tid & 63;
    const int wv   = __builtin_amdgcn_readfirstlane(tid >> 6);
    const int tok0 = blockIdx.x * 16 + wv * 8;
    const float* __restrict__ xw = x + (size_t)tok0 * D_MODEL;

    float2 xcur[8], xnxt[8];
#pragma unroll
    for (int t = 0; t < 8; t++)
        xcur[t] = *(const float2*)(xw + (size_t)t * D_MODEL + 2 * lane);
    float accm[8];
#pragma unroll
    for (int t = 0; t < 8; t++) accm[t] = 0.f;

    for (int c = 0; c < D_MODEL / BK; c++) {
        const int k0 = c * BK;
        if (c + 1 < D_MODEL / BK) {
#pragma unroll
            for (int t = 0; t < 8; t++)
                xnxt[t] = *(const float2*)(xw + (size_t)t * D_MODEL + (k0 + BK) + 2 * lane);
        }
#pragma unroll
        for (int i = 0; i < 16; i++) {
            int n  = i * 128 + tid;
            int dd = n >> 4;
            int e0 = (n & 15) * 4;
            float4 v = *(const float4*)(W + (size_t)(k0 + dd) * NEXP + e0);
            wt[(e0 + 0) * BKP + dd] = v.x;
            wt[(e0 + 1) * BKP + dd] = v.y;
            wt[(e0 + 2) * BKP + dd] = v.z;
            wt[(e0 + 3) * BKP + dd] = v.w;
        }
        __syncthreads();
        float acc[8];
#pragma unroll
        for (int t = 0; t < 8; t++) acc[t] = 0.f;
        const float* wl = &wt[lane * BKP];
#pragma unroll 4
        for (int kk = 0; kk < BK; kk += 4) {
            float4 w4 = *(const float4*)(wl + kk);
            const int l0 = kk >> 1;
#pragma unroll
            for (int t = 0; t < 8; t++) {
                float a = acc[t];
                a = fmaf(rl(xcur[t].x, l0    ), w4.x, a);
                a = fmaf(rl(xcur[t].y, l0    ), w4.y, a);
                a = fmaf(rl(xcur[t].x, l0 + 1), w4.z, a);
                a = fmaf(rl(xcur[t].y, l0 + 1), w4.w, a);
                acc[t] = a;
            }
        }
#pragma unroll
        for (int t = 0; t < 8; t++) accm[t] += acc[t];
        __syncthreads();
#pragma unroll
        for (int t = 0; t < 8; t++) xcur[t] = xnxt[t];
    }

    const float bias = b[lane];
    float* __restrict__ probs_out = out;
    float* __restrict__ top_out   = out + (size_t)NTOK * NEXP;
    float* __restrict__ idx_out   = top_out + (size_t)NTOK * 2;
#pragma unroll 1
    for (int t = 0; t < 8; t++) {
        const int token = tok0 + t;
        float logit = accm[t] + bias;
        float mx = logit;
#pragma unroll
        for (int off = 32; off; off >>= 1) mx = fmaxf(mx, __shfl_xor(mx, off, 64));
        float ex = expf(logit - mx);
        float s = ex;
#pragma unroll
        for (int off = 32; off; off >>= 1) s += __shfl_xor(s, off, 64);
        float p = ex / s;
        probs_out[(size_t)token * NEXP + lane] = p;
        float v = p; int idx = lane;
#pragma unroll
        for (int off = 32; off; off >>= 1) {
            float ov = __shfl_xor(v, off, 64);
            int   oi = __shfl_xor(idx, off, 64);
            if (ov > v || (ov == v && oi < idx)) { v = ov; idx = oi; }
        }
        const float v1 = v; const int i1 = idx;
        v = (lane == i1) ? -1.0f : p; idx = lane;
#pragma unroll
        for (int off = 32; off; off >>= 1) {
            float ov = __shfl_xor(v, off, 64);
            int   oi = __shfl_xor(idx, off, 64);
            if (ov > v || (ov == v && oi < idx)) { v = ov; idx = oi; }
        }
        const float v2 = v; const int i2 = idx;
        if (lane == 0) {
            const float dnm = v1 + v2 + 1e-9f;
            top_out[(size_t)token * 2 + 0] = v1 / dnm;
            top_out[(size_t)token * 2 + 1] = v2 / dnm;
            idx_out[(size_t)token * 2 + 0] = (float)i1;
            idx_out[(size_t)token * 2 + 1] = (float)i2;
        }
    }
}

extern "C" void kernel_launch(void* const* d_in, const int* in_sizes, int n_in,
                              void* d_out, int out_size, void* d_ws, size_t ws_size,
                              hipStream_t stream) {
    const float* x = (const float*)d_in[0];
    const float* W = (const float*)d_in[1];
    const float* b = (const float*)d_in[2];
    float* out = (float*)d_out;

    const size_t need = (size_t)NKS * 4 * 2 * 64 * 16;   // 1 MiB of f16 fragments
    if (ws_size >= need) {
        prep_w<<<128, 256, 0, stream>>>(W, (half8*)d_ws);
        router_mfma<<<256, 256, 0, stream>>>(x, (const int4*)d_ws, b, out);
    } else {
        router_fallback<<<NTOK / 16, 128, 0, stream>>>(x, W, b, out);
    }
}